// Round 10
// baseline (772.426 us; speedup 1.0000x reference)
//
#include <hip/hip_runtime.h>
#include <math.h>

// ---------------------------------------------------------------------------
// EfficientFaceTransformer forward — round 10: attn 16-rows/wave (2x TLP),
// exp2-domain softmax, s_setprio around MFMA.
// ---------------------------------------------------------------------------

#define NPIX 784
#define CDIM 512
#define NHEAD 8
#define C3 1536

typedef unsigned int uint;
typedef unsigned short ushort;
typedef float f32x4 __attribute__((ext_vector_type(4)));
typedef __bf16 bf16x8 __attribute__((ext_vector_type(8)));
typedef __bf16 bf16x2 __attribute__((ext_vector_type(2)));

#define LOG2E 1.4426950408889634f
#define KSCL  0.18033688011112042f   /* 0.125 * log2(e) */

// ---- workspace float offsets ----------------------------------------------
#define OFF_XPM ((size_t)0)
#define OFF_W   ((size_t)3211264)
#define OFF_R2  ((size_t)5324288)
#define OFF_VBF ((size_t)14958080)
#define OFF_OBF ((size_t)18169344)
#define OFF_X2  ((size_t)21380608)
#define OFF_X3  ((size_t)27803136)
#define OFF_PL  ((size_t)34225664)
#define OFF_AD  ((size_t)34233856)
#define OFF_RB  ((size_t)34250240)
#define OFF_US  ((size_t)34250288)
#define OFF_RS  ((size_t)34262832)
#define OFF_E2C ((size_t)34275392)

// weight sub-offsets (ushort units)
#define WOFF_QKV 0
#define WOFF_PROJ 786432
#define WOFF_G1  1048576
#define WOFF_G2  1114112
#define WOFF_FUS 1310720
#define WOFF_E1  2097152

__device__ __forceinline__ ushort f2bf(float f) {
  __bf16 h = (__bf16)f;
  return __builtin_bit_cast(ushort, h);
}
__device__ __forceinline__ unsigned pack2bf(float lo, float hi) {
  bf16x2 v = {(__bf16)lo, (__bf16)hi};
  return __builtin_bit_cast(unsigned, v);
}
__device__ __forceinline__ float bf2f(ushort u) {
  unsigned x = ((unsigned)u) << 16;
  return __builtin_bit_cast(float, x);
}
__device__ __forceinline__ void unpack4bf(uint2 v, float* o) {
  o[0] = bf2f((ushort)(v.x & 0xffffu)); o[1] = bf2f((ushort)(v.x >> 16));
  o[2] = bf2f((ushort)(v.y & 0xffffu)); o[3] = bf2f((ushort)(v.y >> 16));
}

// ---------------------------------------------------------------------------
// pooled[b,c] = SUM_p x[b,c,p]  (consumers apply 1/784)
__global__ __launch_bounds__(64) void pool_mean_k(const float* __restrict__ x,
                                                  float* __restrict__ pooled) {
  int c = blockIdx.x, b = blockIdx.y;
  const float* row = x + ((size_t)b * CDIM + c) * NPIX;
  float s = 0.f;
  for (int i = threadIdx.x; i < NPIX; i += 64) s += row[i];
  #pragma unroll
  for (int off = 32; off; off >>= 1) s += __shfl_down(s, off);
  if (threadIdx.x == 0) pooled[b * CDIM + c] = s;
}

// ---------------------------------------------------------------------------
__global__ __launch_bounds__(256) void adapt_mlp_k(const float* __restrict__ pooled,
                                                   const float* __restrict__ a1w,
                                                   const float* __restrict__ a1b,
                                                   const float* __restrict__ a2w,
                                                   const float* __restrict__ a2b,
                                                   float* __restrict__ ad) {
  int b = blockIdx.x, tid = threadIdx.x;
  __shared__ float pl[CDIM];
  __shared__ float hh[128];
  for (int i = tid; i < CDIM; i += 256)
    pl[i] = pooled[b * CDIM + i] * (1.f / NPIX);
  __syncthreads();
  if (tid < 128) {
    const float* w = a1w + (size_t)tid * CDIM;
    float a = a1b[tid];
    for (int k = 0; k < CDIM; ++k) a += w[k] * pl[k];
    hh[tid] = fmaxf(a, 0.f);
  }
  __syncthreads();
  for (int o = tid; o < 1024; o += 256) {
    const float* w = a2w + (size_t)o * 128;
    float a = a2b[o];
    for (int k = 0; k < 128; ++k) a += w[k] * hh[k];
    ad[b * 1024 + o] = a;
  }
}

// ---------------------------------------------------------------------------
// adaptive LN: read f32 ch-major, write bf16 pixel-major [b][p][512].
template <int STATS>
__global__ __launch_bounds__(256) void ln_pm_k(const float* __restrict__ x,
                                               const float* __restrict__ w,
                                               const float* __restrict__ bias,
                                               const float* __restrict__ ad,
                                               ushort* __restrict__ out,
                                               float* __restrict__ ust,
                                               float* __restrict__ rstp) {
  int b = blockIdx.y;
  int p0 = blockIdx.x * 32;
  int tid = threadIdx.x;
  int px = tid & 31, cg = tid >> 5;
  int p = p0 + px;
  bool valid = p < NPIX;
  const float* xb = x + (size_t)b * CDIM * NPIX;
  float s = 0.f, s2 = 0.f;
  if (valid) {
    for (int c = cg * 64; c < cg * 64 + 64; ++c) {
      float v = xb[(size_t)c * NPIX + p];
      s += v; s2 += v * v;
    }
  }
  __shared__ float rs[8][32], rq[8][32], us[32], vs[32];
  rs[cg][px] = s; rq[cg][px] = s2;
  __syncthreads();
  if (tid < 32) {
    float ts = 0.f, ts2 = 0.f;
    #pragma unroll
    for (int g = 0; g < 8; ++g) { ts += rs[g][tid]; ts2 += rq[g][tid]; }
    float u = ts * (1.f / CDIM);
    float var = ts2 * (1.f / CDIM) - u * u;
    float rv = rsqrtf(var + 1e-6f);
    us[tid] = u; vs[tid] = rv;
    if (STATS && p0 + tid < NPIX) {
      ust[(size_t)b * NPIX + p0 + tid] = u;
      rstp[(size_t)b * NPIX + p0 + tid] = rv;
    }
  }
  __syncthreads();
  if (valid) {
    float u = us[px], rv = vs[px];
    const float* aw = ad + (size_t)b * 1024;
    const float* ab = aw + CDIM;
    ushort* ob = out + ((size_t)(b * NPIX + p)) * CDIM + cg * 64;
    for (int cb = 0; cb < 64; cb += 8) {
      int c = cg * 64 + cb;
      float vv[8];
      #pragma unroll
      for (int q = 0; q < 8; ++q) {
        float v = xb[(size_t)(c + q) * NPIX + p];
        vv[q] = w[c + q] * (1.f + aw[c + q]) * ((v - u) * rv) + (bias[c + q] + ab[c + q]);
      }
      uint4 o = {pack2bf(vv[0], vv[1]), pack2bf(vv[2], vv[3]),
                 pack2bf(vv[4], vv[5]), pack2bf(vv[6], vv[7])};
      *(uint4*)(ob + cb) = o;
    }
  }
}

// ---------------------------------------------------------------------------
// weight convert fp32 -> bf16 with stacking: d[r*ds + cc], zero outside.
struct CvtDesc {
  const float* s[11];
  ushort* d[11];
  int rows[11], sk[11], dk[11], ds[11], rr[11];
};
__global__ __launch_bounds__(256) void cvt_w_k(CvtDesc D) {
  int seg = blockIdx.y;
  int sk = D.sk[seg], dk = D.dk[seg], ds = D.ds[seg], rr = D.rr[seg];
  int total = D.rows[seg] * dk;
  const float* s = D.s[seg];
  ushort* d = D.d[seg];
  for (int i = blockIdx.x * 256 + threadIdx.x; i < total; i += gridDim.x * 256) {
    int r = i / dk, cc = i - r * dk;
    d[(size_t)r * ds + cc] = (cc < sk && r < rr) ? f2bf(s[(size_t)r * sk + cc]) : (ushort)0;
  }
}

// ---------------------------------------------------------------------------
// bias prep: sprpb_bf[h][q][m] = bf16((struct_prior + rpb) * log2e)
__global__ __launch_bounds__(256) void sprpb_k(const float* __restrict__ sp,
                                               const float* __restrict__ rpb,
                                               ushort* __restrict__ out) {
  const int q = blockIdx.x, h = blockIdx.y;
  const int i1 = q / 28, j1 = q - i1 * 28;
  const float* src = sp + ((size_t)h * NPIX + q) * NPIX;
  ushort* dst = out + ((size_t)h * NPIX + q) * NPIX;
  for (int m = threadIdx.x; m < NPIX; m += 256) {
    int i2 = m / 28, j2 = m - i2 * 28;
    float rv = rpb[(size_t)((i1 - i2 + 27) * 55 + (j1 - j2 + 27)) * NHEAD + h];
    dst[m] = f2bf((src[m] + rv) * LOG2E);
  }
}

__global__ __launch_bounds__(256) void fpcvt_k(const float* __restrict__ fp,
                                               ushort* __restrict__ out) {
  size_t i = (size_t)blockIdx.x * 256 + threadIdx.x;
  float4 v = *((const float4*)fp + i);
  ushort4 o;
  o.x = f2bf(v.x); o.y = f2bf(v.y); o.z = f2bf(v.z); o.w = f2bf(v.w);
  *((ushort4*)out + i) = o;
}

// ---------------------------------------------------------------------------
__global__ __launch_bounds__(512) void biaseff_k(const float* __restrict__ rbuf,
                                                 const float* __restrict__ b0,
                                                 const float* __restrict__ b1,
                                                 const float* __restrict__ b2,
                                                 const float* __restrict__ a0,
                                                 const float* __restrict__ a1,
                                                 const float* __restrict__ a2,
                                                 float* __restrict__ be,
                                                 float* __restrict__ e1bcat) {
  int b = blockIdx.x;
  if (b < 16) {
    int n = threadIdx.x;
    be[b * 512 + n] = rbuf[b * 3] * b0[n] + rbuf[b * 3 + 1] * b1[n] + rbuf[b * 3 + 2] * b2[n];
  } else {
    for (int i = threadIdx.x; i < 2112; i += 512) {
      int e = i / 704, r = i - e * 704;
      e1bcat[i] = (r < 682) ? (e == 0 ? a0 : e == 1 ? a1 : a2)[r] : 0.f;
    }
  }
}

// ---------------------------------------------------------------------------
// Universal MFMA GEMM (round-9 structure, unchanged).
template <int ORIENT, int EPI, int POOL, int DUALBF, int BN>
__global__ __launch_bounds__(256) void mgemm_k(const ushort* __restrict__ X,
                                               const ushort* __restrict__ Wt,
                                               const float* __restrict__ bias,
                                               const float* __restrict__ resid,
                                               const float* __restrict__ scales,
                                               void* __restrict__ OutV,
                                               float* __restrict__ pool_out,
                                               ushort* __restrict__ pm_out,
                                               int Ks, int Nreal, int Nstore) {
  constexpr int NFRAG = BN / 64;
  const int bid = blockIdx.x;
  const int xcd = bid & 7;
  const int i = bid >> 3;
  const int mt_local = i % 14;
  const int nt = i / 14;
  const int m0 = (xcd * 14 + mt_local) * 112;
  const int n0 = nt * BN;
  const int bb = m0 / NPIX;
  const int t = threadIdx.x;
  const int w = t >> 6, lane = t & 63, c = lane & 15, g = lane >> 4;
  __shared__ ushort Xs[7168];
  __shared__ ushort Ws[BN * 64];
  f32x4 acc[7][NFRAG];
  #pragma unroll
  for (int mi = 0; mi < 7; ++mi)
    #pragma unroll
    for (int ni = 0; ni < NFRAG; ++ni) acc[mi][ni] = (f32x4){0.f, 0.f, 0.f, 0.f};

  for (int k0 = 0; k0 < Ks; k0 += 64) {
    for (int ii = t; ii < 896; ii += 256) {
      int m = ii >> 3, kg = ii & 7;
      uint4 v = *(const uint4*)(X + (size_t)(m0 + m) * Ks + k0 + kg * 8);
      *(uint4*)&Xs[m * 64 + ((kg ^ (m & 7)) << 3)] = v;
    }
    for (int ii = t; ii < BN * 8; ii += 256) {
      int n = ii >> 3, kg = ii & 7;
      uint4 v = {0u, 0u, 0u, 0u};
      if (n0 + n < Nreal) v = *(const uint4*)(Wt + (size_t)(n0 + n) * Ks + k0 + kg * 8);
      *(uint4*)&Ws[n * 64 + ((kg ^ (n & 7)) << 3)] = v;
    }
    __syncthreads();
    #pragma unroll
    for (int kc = 0; kc < 2; ++kc) {
      bf16x8 xf[7], wf[NFRAG];
      #pragma unroll
      for (int mi = 0; mi < 7; ++mi) {
        int m = mi * 16 + c;
        xf[mi] = *(const bf16x8*)&Xs[m * 64 + (((kc * 4 + g) ^ (m & 7)) << 3)];
      }
      #pragma unroll
      for (int ni = 0; ni < NFRAG; ++ni) {
        int n = w * (16 * NFRAG) + ni * 16 + c;
        wf[ni] = *(const bf16x8*)&Ws[n * 64 + (((kc * 4 + g) ^ (n & 7)) << 3)];
      }
      #pragma unroll
      for (int mi = 0; mi < 7; ++mi)
        #pragma unroll
        for (int ni = 0; ni < NFRAG; ++ni)
          acc[mi][ni] = (ORIENT == 0)
            ? __builtin_amdgcn_mfma_f32_16x16x32_bf16(wf[ni], xf[mi], acc[mi][ni], 0, 0, 0)
            : __builtin_amdgcn_mfma_f32_16x16x32_bf16(xf[mi], wf[ni], acc[mi][ni], 0, 0, 0);
    }
    __syncthreads();
  }

  if (ORIENT == 0) {
    ushort* Ob = (ushort*)OutV;
    const int nbq = n0 + w * (16 * NFRAG);
    float bi[NFRAG][4];
    #pragma unroll
    for (int ni = 0; ni < NFRAG; ++ni)
      #pragma unroll
      for (int j = 0; j < 4; ++j) {
        int n = nbq + ni * 16 + g * 4 + j;
        bi[ni][j] = (n < Nreal) ? bias[n] : 0.f;
      }
    #pragma unroll
    for (int mi = 0; mi < 7; ++mi) {
      int m = m0 + mi * 16 + c;
      #pragma unroll
      for (int ni = 0; ni < NFRAG; ++ni) {
        int nb = nbq + ni * 16 + g * 4;
        if (nb >= Nstore) continue;
        float v[4];
        #pragma unroll
        for (int j = 0; j < 4; ++j) v[j] = acc[mi][ni][j] + bi[ni][j];
        if (EPI == 1) {
          #pragma unroll
          for (int j = 0; j < 4; ++j) v[j] = fmaxf(v[j], 0.f);
        } else if (EPI == 2) {
          #pragma unroll
          for (int j = 0; j < 4; ++j)
            v[j] = 0.5f * v[j] * (1.f + erff(v[j] * 0.70710678118654752f));
        } else if (EPI == 3) {
          uint2 cm = *(const uint2*)&Ob[(size_t)m * Nstore + nb];
          float cf[4];
          unpack4bf(cm, cf);
          #pragma unroll
          for (int j = 0; j < 4; ++j)
            v[j] = (1.f / (1.f + __expf(-v[j]))) * cf[j];
        } else if (EPI == 5) {
          int e = nb / 704; e = (e > 2) ? 2 : e;
          float sc = scales[bb * 3 + e];
          #pragma unroll
          for (int j = 0; j < 4; ++j)
            v[j] = 0.5f * v[j] * (1.f + erff(v[j] * 0.70710678118654752f)) * sc;
        }
        uint2 o = {pack2bf(v[0], v[1]), pack2bf(v[2], v[3])};
        *(uint2*)&Ob[(size_t)m * Nstore + nb] = o;
      }
    }
  } else {
    const int prow = m0 - bb * NPIX;
    float* Ob = (float*)OutV + (size_t)bb * CDIM * NPIX;
    const float* Rb = resid + (size_t)bb * CDIM * NPIX;
    float sc = (EPI == 4 && scales) ? scales[bb * 3] : 1.f;
    #pragma unroll
    for (int ni = 0; ni < NFRAG; ++ni) {
      int n = n0 + w * (16 * NFRAG) + ni * 16 + c;
      float bv = (EPI == 5) ? bias[(size_t)bb * CDIM + n] : bias[n];
      float cs = 0.f;
      #pragma unroll
      for (int mi = 0; mi < 7; ++mi) {
        int p = prow + mi * 16 + g * 4;
        size_t off = (size_t)n * NPIX + p;
        float4 r = *(const float4*)&Rb[off];
        f32x4 a = acc[mi][ni];
        float4 o = {r.x + sc * (a[0] + bv), r.y + sc * (a[1] + bv),
                    r.z + sc * (a[2] + bv), r.w + sc * (a[3] + bv)};
        *(float4*)&Ob[off] = o;
        if (POOL) cs += o.x + o.y + o.z + o.w;
        if (DUALBF) {
          size_t mg = (size_t)(m0 + mi * 16 + g * 4);
          pm_out[mg * CDIM + n] = f2bf(o.x);
          pm_out[(mg + 1) * CDIM + n] = f2bf(o.y);
          pm_out[(mg + 2) * CDIM + n] = f2bf(o.z);
          pm_out[(mg + 3) * CDIM + n] = f2bf(o.w);
        }
      }
      if (POOL) {
        cs += __shfl_xor(cs, 16);
        cs += __shfl_xor(cs, 32);
        if (g == 0) atomicAdd(pool_out + (size_t)bb * CDIM + n, cs);
      }
    }
  }
}

// ---------------------------------------------------------------------------
// transpose V out of qkvbf:  [b][p][1024+c] bf16 -> vbf [b][c][784] bf16
__global__ __launch_bounds__(256) void vtr_k(const ushort* __restrict__ qkvbf,
                                             ushort* __restrict__ vbf) {
  const int p0 = blockIdx.x * 64, c0 = blockIdx.y * 64, b = blockIdx.z;
  __shared__ ushort T[64][72];
  for (int idx = threadIdx.x; idx < 512; idx += 256) {
    int pl = idx >> 3, cq = idx & 7;
    int p = p0 + pl;
    uint4 v = {0u, 0u, 0u, 0u};
    if (p < NPIX)
      v = *(const uint4*)(qkvbf + (size_t)(b * NPIX + p) * C3 + 1024 + c0 + cq * 8);
    *(uint4*)&T[pl][cq * 8] = v;
  }
  __syncthreads();
  for (int idx = threadIdx.x; idx < 512; idx += 256) {
    int cl = idx >> 3, pq = idx & 7;
    if (p0 + pq * 8 < NPIX) {
      ushort tmp[8];
      #pragma unroll
      for (int i = 0; i < 8; ++i) tmp[i] = T[pq * 8 + i][cl];
      *(uint4*)(vbf + ((size_t)(b * CDIM + c0 + cl)) * NPIX + p0 + pq * 8) =
          *(const uint4*)&tmp[0];
    }
  }
}

// ---------------------------------------------------------------------------
// MFMA flash attention: 16 q-rows per wave (49 full waves per (b,h)),
// register software-pipeline, exp2-domain softmax, defer-max, setprio.
// Grid 1664: b = (bid&7) + 8*(i/104); all 104 blocks of a batch on one XCD.
struct KFr { bf16x8 a0, a1, b0, b1; };
struct VFr { bf16x8 v0, v1, v2, v3; };
struct BFr { uint2 sl, fl, sh, fh; };

__global__ __launch_bounds__(256) void attn_mfma_k(const ushort* __restrict__ qkvbf,
                                                   const ushort* __restrict__ vbf,
                                                   const ushort* __restrict__ sprpb,
                                                   const ushort* __restrict__ fpb,
                                                   ushort* __restrict__ obf) {
  const int bid = blockIdx.x;
  const int xcd = bid & 7;
  const int i = bid >> 3;              // 0..207
  const int b = xcd + 8 * (i / 104);
  const int r = i % 104;
  const int h = r & 7;
  const int qt = r >> 3;               // 0..12
  const int w = threadIdx.x >> 6, lane = threadIdx.x & 63;
  const int g = lane >> 4, c = lane & 15;
  const int q0 = qt * 64 + w * 16;
  if (q0 + 16 > NPIX) return;          // 49 full 16-row waves cover 784 exactly
  const int q = q0 + c;

  __shared__ uint BL[4][384];
  uint* bw = BL[w];

  const ushort* qp = qkvbf + (size_t)(b * NPIX + q) * C3 + h * 64 + g * 8;
  const bf16x8 qf0 = *(const bf16x8*)qp;
  const bf16x8 qf1 = *(const bf16x8*)(qp + 32);

  const ushort* kbase = qkvbf + (size_t)b * NPIX * C3 + 512 + h * 64 + g * 8;
  const ushort* vbase = vbf + ((size_t)b * CDIM + h * 64) * NPIX;
  const ushort* spr = sprpb + ((size_t)h * NPIX + q) * NPIX;
  const ushort* fp = fpb + ((size_t)b * NPIX + q) * NPIX;

  auto load_k = [&](int m0, bool tfull) -> KFr {
    KFr k;
    const ushort* kp = kbase + (size_t)(m0 + c) * C3;
    k.a0 = *(const bf16x8*)kp;
    k.a1 = *(const bf16x8*)(kp + 32);
    const ushort* kp1 = kp + (tfull ? (size_t)16 * C3 : 0);
    k.b0 = *(const bf16x8*)kp1;
    k.b1 = *(const bf16x8*)(kp1 + 32);
    return k;
  };
  auto load_v = [&](int m0) -> VFr {
    VFr v;
    const ushort* vp = vbase + (size_t)c * NPIX + m0 + g * 8;
    v.v0 = *(const bf16x8*)(vp);
    v.v1 = *(const bf16x8*)(vp + (size_t)16 * NPIX);
    v.v2 = *(const bf16x8*)(vp + (size_t)32 * NPIX);
    v.v3 = *(const bf16x8*)(vp + (size_t)48 * NPIX);
    return v;
  };
  auto load_b = [&](int m0) -> BFr {
    BFr x;
    x.sl = *(const uint2*)(spr + m0 + g * 4);
    x.fl = *(const uint2*)(fp + m0 + g * 4);
    x.sh = *(const uint2*)(spr + m0 + 16 + g * 4);
    x.fh = *(const uint2*)(fp + m0 + 16 + g * 4);
    return x;
  };

  f32x4 o0 = {0.f, 0.f, 0.f, 0.f}, o1 = o0, o2 = o0, o3 = o0;
  float M = -1e30f, L = 0.f;

  KFr kc = load_k(0, true);
  VFr vc = load_v(0);
  BFr bc = load_b(0);

  for (int ms = 0; ms < 25; ++ms) {
    const int m0 = ms * 32;
    const bool full = (ms < 24);

    KFr kn; VFr vn; BFr bn;
    if (full) {
      const int nm0 = m0 + 32;
      kn = load_k(nm0, ms + 1 < 24);
      vn = load_v(nm0);
      bn = load_b(nm0);
    }

    // ---- QK^T ----
    f32x4 s0 = {0.f, 0.f, 0.f, 0.f}, s1 = s0;
    __builtin_amdgcn_s_setprio(1);
    s0 = __builtin_amdgcn_mfma_f32_16x16x32_bf16(kc.a0, qf0, s0, 0, 0, 0);
    s0 = __builtin_amdgcn_mfma_f32_16x16x32_bf16(kc.a1, qf1, s0, 0, 0, 0);
    if (full) {
      s1 = __builtin_amdgcn_mfma_f32_16x16x32_bf16(kc.b0, qf0, s1, 0, 0, 0);
      s1 = __builtin_amdgcn_mfma_f32_16x16x32_bf16(kc.b1, qf1, s1, 0, 0, 0);
    }
    __builtin_amdgcn_s_setprio(0);

    // ---- biases (exp2-domain): v' = (s*0.125 + spr)*fp*log2e ----
    float v0[4], v1[4];
    {
      float spv[4], fpv[4];
      unpack4bf(bc.sl, spv);
      unpack4bf(bc.fl, fpv);
      #pragma unroll
      for (int j = 0; j < 4; ++j) v0[j] = fmaf(s0[j], KSCL, spv[j]) * fpv[j];
      if (full) {
        unpack4bf(bc.sh, spv);
        unpack4bf(bc.fh, fpv);
        #pragma unroll
        for (int j = 0; j < 4; ++j) v1[j] = fmaf(s1[j], KSCL, spv[j]) * fpv[j];
      }
    }

    // ---- online softmax (exp2), defer-max ----
    {
      float tm = fmaxf(fmaxf(v0[0], v0[1]), fmaxf(v0[2], v0[3]));
      if (full) tm = fmaxf(tm, fmaxf(fmaxf(v1[0], v1[1]), fmaxf(v1[2], v1[3])));
      tm = fmaxf(tm, __shfl_xor(tm, 16));
      tm = fmaxf(tm, __shfl_xor(tm, 32));
      if (__any(tm > M)) {
        const float nM = fmaxf(M, tm);
        const float fac = __builtin_amdgcn_exp2f(M - nM);
        L *= fac;
        #pragma unroll
        for (int j = 0; j < 4; ++j) { o0[j] *= fac; o1[j] *= fac; o2[j] *= fac; o3[j] *= fac; }
        M = nM;
      }
      float p0v[4], p1v[4];
      float ps = 0.f;
      #pragma unroll
      for (int j = 0; j < 4; ++j) { p0v[j] = __builtin_amdgcn_exp2f(v0[j] - M); ps += p0v[j]; }
      if (full) {
        #pragma unroll
        for (int j = 0; j < 4; ++j) { p1v[j] = __builtin_amdgcn_exp2f(v1[j] - M); ps += p1v[j]; }
      }
      ps += __shfl_xor(ps, 16);
      ps += __shfl_xor(ps, 32);
      L += ps;
      uint2 wlo, whi;
      wlo.x = pack2bf(p0v[0], p0v[1]);
      wlo.y = pack2bf(p0v[2], p0v[3]);
      whi.x = full ? pack2bf(p1v[0], p1v[1]) : 0u;
      whi.y = full ? pack2bf(p1v[2], p1v[3]) : 0u;
      *(uint2*)&bw[lane * 6] = wlo;
      *(uint2*)&bw[lane * 6 + 2] = whi;
    }

    // ---- PV ----
    const int f = g >> 1;
    const int slo = 32 * (g & 1) + c;
    uint2 blo = *(const uint2*)&bw[slo * 6 + f * 2];
    uint2 bhi = *(const uint2*)&bw[(slo + 16) * 6 + f * 2];
    uint4 bba = {blo.x, blo.y, bhi.x, bhi.y};
    const bf16x8 pf = __builtin_bit_cast(bf16x8, bba);
    __builtin_amdgcn_s_setprio(1);
    o0 = __builtin_amdgcn_mfma_f32_16x16x32_bf16(vc.v0, pf, o0, 0, 0, 0);
    o1 = __builtin_amdgcn_mfma_f32_16x16x32_bf16(vc.v1, pf, o1, 0, 0, 0);
    o2 = __builtin_amdgcn_mfma_f32_16x16x32_bf16(vc.v2, pf, o2, 0, 0, 0);
    o3 = __builtin_amdgcn_mfma_f32_16x16x32_bf16(vc.v3, pf, o3, 0, 0, 0);
    __builtin_amdgcn_s_setprio(0);

    if (full) { kc = kn; vc = vn; bc = bn; }
  }

  {
    const float invL = 1.f / L;
    ushort* dst = obf + (size_t)(b * NPIX + q) * CDIM + h * 64 + g * 4;
    f32x4 ot[4] = {o0, o1, o2, o3};
    #pragma unroll
    for (int t2 = 0; t2 < 4; ++t2) {
      uint2 o = {pack2bf(ot[t2][0] * invL, ot[t2][1] * invL),
                 pack2bf(ot[t2][2] * invL, ot[t2][3] * invL)};
      *(uint2*)(dst + t2 * 16) = o;
    }
  }
}

// ---------------------------------------------------------------------------
// Sliding-window fused LN2 + depthwise conv (3x3/5x5/7x7) -> cat pm bf16.
__device__ __forceinline__ float bf2f_s(ushort u) { return bf2f(u); }

template <int R>
__device__ __forceinline__ void conv_pass(const ushort* __restrict__ plane_ci,
                                          const float* __restrict__ wl_ci,
                                          float bv, int slot,
                                          ushort (*__restrict__ outb)[16], int ci) {
  constexpr int K = 2 * R + 1;
  float wreg[K * K];
  #pragma unroll
  for (int i = 0; i < K * K; ++i) wreg[i] = wl_ci[i];
  #pragma unroll
  for (int r7 = 0; r7 < 7; ++r7) {
    const int run = slot + r7 * 16;
    const int y = run >> 2, x0 = (run & 3) * 7;
    float acc[7];
    #pragma unroll
    for (int i = 0; i < 7; ++i) acc[i] = bv;
    #pragma unroll
    for (int dy = 0; dy < K; ++dy) {
      const ushort* rp = plane_ci + (y + 3 - R + dy) * 34 + (x0 + 3 - R);
      float win[7 + 2 * R];
      #pragma unroll
      for (int k = 0; k < 7 + 2 * R; ++k) win[k] = bf2f_s(rp[k]);
      #pragma unroll
      for (int i = 0; i < 7; ++i)
        #pragma unroll
        for (int k = 0; k < K; ++k)
          acc[i] = fmaf(win[i + k], wreg[dy * K + k], acc[i]);
    }
    #pragma unroll
    for (int i = 0; i < 7; ++i) outb[y * 28 + x0 + i][ci] = f2bf(acc[i]);
  }
}

__global__ __launch_bounds__(256) void dwln_k(const float* __restrict__ x2,
    const float* __restrict__ ust, const float* __restrict__ rst,
    const float* __restrict__ ad, const float* __restrict__ n2w,
    const float* __restrict__ n2b,
    const float* __restrict__ ew, const float* __restrict__ eb,
    const float* __restrict__ nw, const float* __restrict__ nb,
    const float* __restrict__ mw, const float* __restrict__ mb,
    ushort* __restrict__ cat) {
  const int cg = blockIdx.x, b = blockIdx.y;
  const int c0 = cg * 16;
  const int t = threadIdx.x;
  const int ci = t & 15, slot = t >> 4;

  __shared__ ushort plane[16][1156];
  __shared__ ushort outb[784][16];
  __shared__ float Wl[16 * 49];
  __shared__ float LWs[16], LBs[16];

  {
    uint* pz = (uint*)&plane[0][0];
    for (int i = t; i < 16 * 1156 / 2; i += 256) pz[i] = 0u;
  }
  if (t < 16) {
    int cc = c0 + t;
    float aw = ad[b * 1024 + cc], ab = ad[b * 1024 + 512 + cc];
    LWs[t] = n2w[cc] * (1.f + aw);
    LBs[t] = n2b[cc] + ab;
  }
  __syncthreads();

  {
    float uu[4], rr[4];
    #pragma unroll
    for (int j = 0; j < 4; ++j) {
      int p = t + j * 256;
      if (p < NPIX) {
        uu[j] = ust[(size_t)b * NPIX + p];
        rr[j] = rst[(size_t)b * NPIX + p];
      }
    }
    for (int cc = 0; cc < 16; ++cc) {
      const float* xp = x2 + ((size_t)(b * CDIM + c0 + cc)) * NPIX;
      float lw = LWs[cc], lb = LBs[cc];
      #pragma unroll
      for (int j = 0; j < 4; ++j) {
        int p = t + j * 256;
        if (p < NPIX) {
          int y = p / 28, xx2 = p - y * 28;
          plane[cc][(y + 3) * 34 + xx2 + 3] = f2bf(lw * (xp[p] - uu[j]) * rr[j] + lb);
        }
      }
    }
  }
  __syncthreads();

  #pragma unroll 1
  for (int cv = 0; cv < 3; ++cv) {
    const float* gw = (cv == 0) ? ew : (cv == 1) ? nw : mw;
    const float* gb = (cv == 0) ? eb : (cv == 1) ? nb : mb;
    const int K2 = (cv == 0) ? 9 : (cv == 1) ? 25 : 49;
    for (int i = t; i < 16 * K2; i += 256) {
      int cc = i / K2, k = i - cc * K2;
      Wl[cc * K2 + k] = gw[(size_t)(c0 + cc) * K2 + k];
    }
    __syncthreads();
    float bv = gb[c0 + ci];
    if (cv == 0)      conv_pass<1>(&plane[ci][0], &Wl[ci * 9],  bv, slot, outb, ci);
    else if (cv == 1) conv_pass<2>(&plane[ci][0], &Wl[ci * 25], bv, slot, outb, ci);
    else              conv_pass<3>(&plane[ci][0], &Wl[ci * 49], bv, slot, outb, ci);
    __syncthreads();
    for (int idx = t; idx < NPIX * 2; idx += 256) {
      int p = idx >> 1, half = idx & 1;
      uint4 v = *(const uint4*)&outb[p][half * 8];
      *(uint4*)(cat + ((size_t)(b * NPIX + p)) * C3 + cv * 512 + c0 + half * 8) = v;
    }
    __syncthreads();
  }
}

// ---------------------------------------------------------------------------
__global__ __launch_bounds__(64) void router_k(const float* __restrict__ pooled,
                                               const float* __restrict__ rw,
                                               const float* __restrict__ rb,
                                               float* __restrict__ r) {
  int b = blockIdx.x, lane = threadIdx.x;
  float a0 = 0.f, a1 = 0.f, a2 = 0.f;
  for (int k = lane; k < CDIM; k += 64) {
    float p = pooled[b * CDIM + k] * (1.f / NPIX);
    a0 += rw[k] * p;
    a1 += rw[CDIM + k] * p;
    a2 += rw[2 * CDIM + k] * p;
  }
  #pragma unroll
  for (int off = 32; off; off >>= 1) {
    a0 += __shfl_down(a0, off);
    a1 += __shfl_down(a1, off);
    a2 += __shfl_down(a2, off);
  }
  if (lane == 0) {
    float l0 = a0 + rb[0], l1 = a1 + rb[1], l2 = a2 + rb[2];
    float mx = fmaxf(l0, fmaxf(l1, l2));
    float e0 = __expf(l0 - mx), e1 = __expf(l1 - mx), e2 = __expf(l2 - mx);
    float inv = 1.f / (e0 + e1 + e2);
    r[b * 3 + 0] = e0 * inv;
    r[b * 3 + 1] = e1 * inv;
    r[b * 3 + 2] = e2 * inv;
  }
}

// ---------------------------------------------------------------------------
extern "C" void kernel_launch(void* const* d_in, const int* in_sizes, int n_in,
                              void* d_out, int out_size, void* d_ws, size_t ws_size,
                              hipStream_t stream) {
  (void)in_sizes; (void)n_in; (void)out_size; (void)ws_size;
  const float* x         = (const float*)d_in[0];
  const float* fpri      = (const float*)d_in[1];
  const float* n1_w      = (const float*)d_in[2];
  const float* n1_b      = (const float*)d_in[3];
  const float* n1_a1w    = (const float*)d_in[4];
  const float* n1_a1b    = (const float*)d_in[5];
  const float* n1_a2w    = (const float*)d_in[6];
  const float* n1_a2b    = (const float*)d_in[7];
  const float* n2_w      = (const float*)d_in[8];
  const float* n2_b      = (const float*)d_in[9];
  const float* n2_a1w    = (const float*)d_in[10];
  const float* n2_a1b    = (const float*)d_in[11];
  const float* n2_a2w    = (const float*)d_in[12];
  const float* n2_a2b    = (const float*)d_in[13];
  const float* qkv_w     = (const float*)d_in[14];
  const float* qkv_b     = (const float*)d_in[15];
  const float* rpb_table = (const float*)d_in[16];
  const float* sprior    = (const float*)d_in[17];
  const float* proj_w    = (const float*)d_in[18];
  const float* proj_b    = (const float*)d_in[19];
  const float* eye_w     = (const float*)d_in[20];
  const float* eye_b     = (const float*)d_in[21];
  const float* nose_w    = (const float*)d_in[22];
  const float* nose_b    = (const float*)d_in[23];
  const float* mouth_w   = (const float*)d_in[24];
  const float* mouth_b   = (const float*)d_in[25];
  const float* fusion_w  = (const float*)d_in[26];
  const float* fusion_b  = (const float*)d_in[27];
  const float* gate1_w   = (const float*)d_in[28];
  const float* gate1_b   = (const float*)d_in[29];
  const float* gate2_w   = (const float*)d_in[30];
  const float* gate2_b   = (const float*)d_in[31];
  const float* e1w[3] = {(const float*)d_in[32], (const float*)d_in[36], (const float*)d_in[40]};
  const float* e1b[3] = {(const float*)d_in[33], (const float*)d_in[37], (const float*)d_in[41]};
  const float* e2w[3] = {(const float*)d_in[34], (const float*)d_in[38], (const float*)d_in[42]};
  const float* e2b[3] = {(const float*)d_in[35], (const float*)d_in[39], (const float*)d_in[43]};
  const float* router_w  = (const float*)d_in[44];
  const float* router_b  = (const float*)d_in[45];

  float* ws    = (float*)d_ws;
  ushort* xpm  = (ushort*)(ws + OFF_XPM);
  ushort* wb   = (ushort*)(ws + OFF_W);
  ushort* r2u  = (ushort*)(ws + OFF_R2);
  ushort* vbf  = (ushort*)(ws + OFF_VBF);
  ushort* obf  = (ushort*)(ws + OFF_OBF);
  float* x2    = ws + OFF_X2;
  float* x3    = ws + OFF_X3;
  float* pld   = ws + OFF_PL;
  float* adb   = ws + OFF_AD;
  float* rbuf  = ws + OFF_RB;
  float* ust   = ws + OFF_US;
  float* rst   = ws + OFF_RS;
  float* outp  = (float*)d_out;

  ushort* qkvw  = wb + WOFF_QKV;
  ushort* projw = wb + WOFF_PROJ;
  ushort* g1w   = wb + WOFF_G1;
  ushort* g2w   = wb + WOFF_G2;
  ushort* fusw  = wb + WOFF_FUS;
  ushort* e1cat = wb + WOFF_E1;
  ushort* e2cat = (ushort*)(ws + OFF_E2C);
  float* be     = adb;
  float* e1bcat = adb + 8192;

  ushort* fpbf   = (ushort*)x2;
  ushort* sprpbf = (ushort*)x3;

  // --- weight conversion + expert stacking (704-aligned) ---
  CvtDesc D;
  auto seg = [&](int s2, const float* src, ushort* dst, int rows, int sk, int dk,
                 int ds, int rr) {
    D.s[s2] = src; D.d[s2] = dst; D.rows[s2] = rows; D.sk[s2] = sk;
    D.dk[s2] = dk; D.ds[s2] = ds; D.rr[s2] = rr;
  };
  seg(0, qkv_w,    qkvw,  1536, 512,  512,  512,  1536);
  seg(1, proj_w,   projw, 512,  512,  512,  512,  512);
  seg(2, gate1_w,  g1w,   128,  512,  512,  512,  128);
  seg(3, gate2_w,  g2w,   1536, 128,  128,  128,  1536);
  seg(4, fusion_w, fusw,  512,  1536, 1536, 1536, 512);
  for (int e = 0; e < 3; ++e) {
    seg(5 + e, e1w[e], e1cat + (size_t)e * 704 * 512, 704, 512, 512, 512, 682);
    seg(8 + e, e2w[e], e2cat + (size_t)e * 704,       512, 682, 704, 2112, 512);
  }
  cvt_w_k<<<dim3(512, 11), 256, 0, stream>>>(D);

  // --- attention bias prep ---
  sprpb_k<<<dim3(NPIX, NHEAD), 256, 0, stream>>>(sprior, rpb_table, sprpbf);
  fpcvt_k<<<9604, 256, 0, stream>>>(fpri, fpbf);

  // --- LN1 ---
  pool_mean_k<<<dim3(CDIM, 16), 64, 0, stream>>>(x, pld);
  adapt_mlp_k<<<16, 256, 0, stream>>>(pld, n1_a1w, n1_a1b, n1_a2w, n1_a2b, adb);
  ln_pm_k<0><<<dim3(25, 16), 256, 0, stream>>>(x, n1_w, n1_b, adb, xpm, nullptr, nullptr);

  // --- attention ---
  mgemm_k<0, 0, 0, 0, 128><<<1344, 256, 0, stream>>>(xpm, qkvw, qkv_b, nullptr, nullptr,
                                                     r2u, nullptr, nullptr, 512, 1536, 1536);
  vtr_k<<<dim3(13, 8, 16), 256, 0, stream>>>(r2u, vbf);
  attn_mfma_k<<<1664, 256, 0, stream>>>(r2u, vbf, sprpbf, fpbf, obf);
  hipMemsetAsync(pld, 0, 16 * CDIM * sizeof(float), stream);
  mgemm_k<1, 4, 1, 0, 64><<<896, 256, 0, stream>>>(obf, projw, proj_b, x, nullptr,
                                                   x2, pld, nullptr, 512, 512, 512);

  // --- LN2 + token mixer ---
  adapt_mlp_k<<<16, 256, 0, stream>>>(pld, n2_a1w, n2_a1b, n2_a2w, n2_a2b, adb);
  ln_pm_k<1><<<dim3(25, 16), 256, 0, stream>>>(x2, n2_w, n2_b, adb, xpm, ust, rst);
  dwln_k<<<dim3(32, 16), 256, 0, stream>>>(x2, ust, rst, adb, n2_w, n2_b,
                                           eye_w, eye_b, nose_w, nose_b, mouth_w, mouth_b,
                                           r2u);
  mgemm_k<0, 1, 0, 0, 64><<<224, 256, 0, stream>>>(xpm, g1w, gate1_b, nullptr, nullptr,
                                                   obf, nullptr, nullptr, 512, 128, 128);
  mgemm_k<0, 3, 0, 0, 128><<<1344, 256, 0, stream>>>(obf, g2w, gate2_b, nullptr, nullptr,
                                                     r2u, nullptr, nullptr, 128, 1536, 1536);
  hipMemsetAsync(pld, 0, 16 * CDIM * sizeof(float), stream);
  mgemm_k<1, 4, 1, 1, 64><<<896, 256, 0, stream>>>(r2u, fusw, fusion_b, x2, nullptr,
                                                   x3, pld, xpm, 1536, 512, 512);

  // --- MoE (fused: 2 stacked GEMMs; x3bf already in xpm via DUALBF) ---
  router_k<<<16, 64, 0, stream>>>(pld, router_w, router_b, rbuf);
  biaseff_k<<<17, 512, 0, stream>>>(rbuf, e2b[0], e2b[1], e2b[2],
                                    e1b[0], e1b[1], e1b[2], be, e1bcat);
  mgemm_k<0, 5, 0, 0, 128><<<1904, 256, 0, stream>>>(xpm, e1cat, e1bcat, nullptr, rbuf,
                                                     r2u, nullptr, nullptr, 512, 2112, 2112);
  mgemm_k<1, 5, 0, 0, 64><<<896, 256, 0, stream>>>(r2u, e2cat, be, x3, nullptr,
                                                   outp, nullptr, nullptr, 2112, 512, 512);
}

// Round 11
// 719.529 us; speedup vs baseline: 1.0735x; 1.0735x over previous
//
#include <hip/hip_runtime.h>
#include <math.h>

// ---------------------------------------------------------------------------
// EfficientFaceTransformer forward — round 11: revert attn to 32-rows/wave
// 2-chunk pipeline (r9 structure, measured best) + exp2 softmax + setprio.
// ---------------------------------------------------------------------------

#define NPIX 784
#define CDIM 512
#define NHEAD 8
#define C3 1536

typedef unsigned int uint;
typedef unsigned short ushort;
typedef float f32x4 __attribute__((ext_vector_type(4)));
typedef __bf16 bf16x8 __attribute__((ext_vector_type(8)));
typedef __bf16 bf16x2 __attribute__((ext_vector_type(2)));

#define LOG2E 1.4426950408889634f
#define KSCL  0.18033688011112042f   /* 0.125 * log2(e) */

// ---- workspace float offsets ----------------------------------------------
#define OFF_XPM ((size_t)0)
#define OFF_W   ((size_t)3211264)
#define OFF_R2  ((size_t)5324288)
#define OFF_VBF ((size_t)14958080)
#define OFF_OBF ((size_t)18169344)
#define OFF_X2  ((size_t)21380608)
#define OFF_X3  ((size_t)27803136)
#define OFF_PL  ((size_t)34225664)
#define OFF_AD  ((size_t)34233856)
#define OFF_RB  ((size_t)34250240)
#define OFF_US  ((size_t)34250288)
#define OFF_RS  ((size_t)34262832)
#define OFF_E2C ((size_t)34275392)

// weight sub-offsets (ushort units)
#define WOFF_QKV 0
#define WOFF_PROJ 786432
#define WOFF_G1  1048576
#define WOFF_G2  1114112
#define WOFF_FUS 1310720
#define WOFF_E1  2097152

__device__ __forceinline__ ushort f2bf(float f) {
  __bf16 h = (__bf16)f;
  return __builtin_bit_cast(ushort, h);
}
__device__ __forceinline__ unsigned pack2bf(float lo, float hi) {
  bf16x2 v = {(__bf16)lo, (__bf16)hi};
  return __builtin_bit_cast(unsigned, v);
}
__device__ __forceinline__ float bf2f(ushort u) {
  unsigned x = ((unsigned)u) << 16;
  return __builtin_bit_cast(float, x);
}
__device__ __forceinline__ void unpack4bf(uint2 v, float* o) {
  o[0] = bf2f((ushort)(v.x & 0xffffu)); o[1] = bf2f((ushort)(v.x >> 16));
  o[2] = bf2f((ushort)(v.y & 0xffffu)); o[3] = bf2f((ushort)(v.y >> 16));
}

// ---------------------------------------------------------------------------
// pooled[b,c] = SUM_p x[b,c,p]  (consumers apply 1/784)
__global__ __launch_bounds__(64) void pool_mean_k(const float* __restrict__ x,
                                                  float* __restrict__ pooled) {
  int c = blockIdx.x, b = blockIdx.y;
  const float* row = x + ((size_t)b * CDIM + c) * NPIX;
  float s = 0.f;
  for (int i = threadIdx.x; i < NPIX; i += 64) s += row[i];
  #pragma unroll
  for (int off = 32; off; off >>= 1) s += __shfl_down(s, off);
  if (threadIdx.x == 0) pooled[b * CDIM + c] = s;
}

// ---------------------------------------------------------------------------
__global__ __launch_bounds__(256) void adapt_mlp_k(const float* __restrict__ pooled,
                                                   const float* __restrict__ a1w,
                                                   const float* __restrict__ a1b,
                                                   const float* __restrict__ a2w,
                                                   const float* __restrict__ a2b,
                                                   float* __restrict__ ad) {
  int b = blockIdx.x, tid = threadIdx.x;
  __shared__ float pl[CDIM];
  __shared__ float hh[128];
  for (int i = tid; i < CDIM; i += 256)
    pl[i] = pooled[b * CDIM + i] * (1.f / NPIX);
  __syncthreads();
  if (tid < 128) {
    const float* w = a1w + (size_t)tid * CDIM;
    float a = a1b[tid];
    for (int k = 0; k < CDIM; ++k) a += w[k] * pl[k];
    hh[tid] = fmaxf(a, 0.f);
  }
  __syncthreads();
  for (int o = tid; o < 1024; o += 256) {
    const float* w = a2w + (size_t)o * 128;
    float a = a2b[o];
    for (int k = 0; k < 128; ++k) a += w[k] * hh[k];
    ad[b * 1024 + o] = a;
  }
}

// ---------------------------------------------------------------------------
// adaptive LN: read f32 ch-major, write bf16 pixel-major [b][p][512].
template <int STATS>
__global__ __launch_bounds__(256) void ln_pm_k(const float* __restrict__ x,
                                               const float* __restrict__ w,
                                               const float* __restrict__ bias,
                                               const float* __restrict__ ad,
                                               ushort* __restrict__ out,
                                               float* __restrict__ ust,
                                               float* __restrict__ rstp) {
  int b = blockIdx.y;
  int p0 = blockIdx.x * 32;
  int tid = threadIdx.x;
  int px = tid & 31, cg = tid >> 5;
  int p = p0 + px;
  bool valid = p < NPIX;
  const float* xb = x + (size_t)b * CDIM * NPIX;
  float s = 0.f, s2 = 0.f;
  if (valid) {
    for (int c = cg * 64; c < cg * 64 + 64; ++c) {
      float v = xb[(size_t)c * NPIX + p];
      s += v; s2 += v * v;
    }
  }
  __shared__ float rs[8][32], rq[8][32], us[32], vs[32];
  rs[cg][px] = s; rq[cg][px] = s2;
  __syncthreads();
  if (tid < 32) {
    float ts = 0.f, ts2 = 0.f;
    #pragma unroll
    for (int g = 0; g < 8; ++g) { ts += rs[g][tid]; ts2 += rq[g][tid]; }
    float u = ts * (1.f / CDIM);
    float var = ts2 * (1.f / CDIM) - u * u;
    float rv = rsqrtf(var + 1e-6f);
    us[tid] = u; vs[tid] = rv;
    if (STATS && p0 + tid < NPIX) {
      ust[(size_t)b * NPIX + p0 + tid] = u;
      rstp[(size_t)b * NPIX + p0 + tid] = rv;
    }
  }
  __syncthreads();
  if (valid) {
    float u = us[px], rv = vs[px];
    const float* aw = ad + (size_t)b * 1024;
    const float* ab = aw + CDIM;
    ushort* ob = out + ((size_t)(b * NPIX + p)) * CDIM + cg * 64;
    for (int cb = 0; cb < 64; cb += 8) {
      int c = cg * 64 + cb;
      float vv[8];
      #pragma unroll
      for (int q = 0; q < 8; ++q) {
        float v = xb[(size_t)(c + q) * NPIX + p];
        vv[q] = w[c + q] * (1.f + aw[c + q]) * ((v - u) * rv) + (bias[c + q] + ab[c + q]);
      }
      uint4 o = {pack2bf(vv[0], vv[1]), pack2bf(vv[2], vv[3]),
                 pack2bf(vv[4], vv[5]), pack2bf(vv[6], vv[7])};
      *(uint4*)(ob + cb) = o;
    }
  }
}

// ---------------------------------------------------------------------------
// weight convert fp32 -> bf16 with stacking: d[r*ds + cc], zero outside.
struct CvtDesc {
  const float* s[11];
  ushort* d[11];
  int rows[11], sk[11], dk[11], ds[11], rr[11];
};
__global__ __launch_bounds__(256) void cvt_w_k(CvtDesc D) {
  int seg = blockIdx.y;
  int sk = D.sk[seg], dk = D.dk[seg], ds = D.ds[seg], rr = D.rr[seg];
  int total = D.rows[seg] * dk;
  const float* s = D.s[seg];
  ushort* d = D.d[seg];
  for (int i = blockIdx.x * 256 + threadIdx.x; i < total; i += gridDim.x * 256) {
    int r = i / dk, cc = i - r * dk;
    d[(size_t)r * ds + cc] = (cc < sk && r < rr) ? f2bf(s[(size_t)r * sk + cc]) : (ushort)0;
  }
}

// ---------------------------------------------------------------------------
// bias prep: sprpb_bf[h][q][m] = bf16((struct_prior + rpb) * log2e)
__global__ __launch_bounds__(256) void sprpb_k(const float* __restrict__ sp,
                                               const float* __restrict__ rpb,
                                               ushort* __restrict__ out) {
  const int q = blockIdx.x, h = blockIdx.y;
  const int i1 = q / 28, j1 = q - i1 * 28;
  const float* src = sp + ((size_t)h * NPIX + q) * NPIX;
  ushort* dst = out + ((size_t)h * NPIX + q) * NPIX;
  for (int m = threadIdx.x; m < NPIX; m += 256) {
    int i2 = m / 28, j2 = m - i2 * 28;
    float rv = rpb[(size_t)((i1 - i2 + 27) * 55 + (j1 - j2 + 27)) * NHEAD + h];
    dst[m] = f2bf((src[m] + rv) * LOG2E);
  }
}

__global__ __launch_bounds__(256) void fpcvt_k(const float* __restrict__ fp,
                                               ushort* __restrict__ out) {
  size_t i = (size_t)blockIdx.x * 256 + threadIdx.x;
  float4 v = *((const float4*)fp + i);
  ushort4 o;
  o.x = f2bf(v.x); o.y = f2bf(v.y); o.z = f2bf(v.z); o.w = f2bf(v.w);
  *((ushort4*)out + i) = o;
}

// ---------------------------------------------------------------------------
__global__ __launch_bounds__(512) void biaseff_k(const float* __restrict__ rbuf,
                                                 const float* __restrict__ b0,
                                                 const float* __restrict__ b1,
                                                 const float* __restrict__ b2,
                                                 const float* __restrict__ a0,
                                                 const float* __restrict__ a1,
                                                 const float* __restrict__ a2,
                                                 float* __restrict__ be,
                                                 float* __restrict__ e1bcat) {
  int b = blockIdx.x;
  if (b < 16) {
    int n = threadIdx.x;
    be[b * 512 + n] = rbuf[b * 3] * b0[n] + rbuf[b * 3 + 1] * b1[n] + rbuf[b * 3 + 2] * b2[n];
  } else {
    for (int i = threadIdx.x; i < 2112; i += 512) {
      int e = i / 704, r = i - e * 704;
      e1bcat[i] = (r < 682) ? (e == 0 ? a0 : e == 1 ? a1 : a2)[r] : 0.f;
    }
  }
}

// ---------------------------------------------------------------------------
// Universal MFMA GEMM (round-9 structure, unchanged).
template <int ORIENT, int EPI, int POOL, int DUALBF, int BN>
__global__ __launch_bounds__(256) void mgemm_k(const ushort* __restrict__ X,
                                               const ushort* __restrict__ Wt,
                                               const float* __restrict__ bias,
                                               const float* __restrict__ resid,
                                               const float* __restrict__ scales,
                                               void* __restrict__ OutV,
                                               float* __restrict__ pool_out,
                                               ushort* __restrict__ pm_out,
                                               int Ks, int Nreal, int Nstore) {
  constexpr int NFRAG = BN / 64;
  const int bid = blockIdx.x;
  const int xcd = bid & 7;
  const int i = bid >> 3;
  const int mt_local = i % 14;
  const int nt = i / 14;
  const int m0 = (xcd * 14 + mt_local) * 112;
  const int n0 = nt * BN;
  const int bb = m0 / NPIX;
  const int t = threadIdx.x;
  const int w = t >> 6, lane = t & 63, c = lane & 15, g = lane >> 4;
  __shared__ ushort Xs[7168];
  __shared__ ushort Ws[BN * 64];
  f32x4 acc[7][NFRAG];
  #pragma unroll
  for (int mi = 0; mi < 7; ++mi)
    #pragma unroll
    for (int ni = 0; ni < NFRAG; ++ni) acc[mi][ni] = (f32x4){0.f, 0.f, 0.f, 0.f};

  for (int k0 = 0; k0 < Ks; k0 += 64) {
    for (int ii = t; ii < 896; ii += 256) {
      int m = ii >> 3, kg = ii & 7;
      uint4 v = *(const uint4*)(X + (size_t)(m0 + m) * Ks + k0 + kg * 8);
      *(uint4*)&Xs[m * 64 + ((kg ^ (m & 7)) << 3)] = v;
    }
    for (int ii = t; ii < BN * 8; ii += 256) {
      int n = ii >> 3, kg = ii & 7;
      uint4 v = {0u, 0u, 0u, 0u};
      if (n0 + n < Nreal) v = *(const uint4*)(Wt + (size_t)(n0 + n) * Ks + k0 + kg * 8);
      *(uint4*)&Ws[n * 64 + ((kg ^ (n & 7)) << 3)] = v;
    }
    __syncthreads();
    #pragma unroll
    for (int kc = 0; kc < 2; ++kc) {
      bf16x8 xf[7], wf[NFRAG];
      #pragma unroll
      for (int mi = 0; mi < 7; ++mi) {
        int m = mi * 16 + c;
        xf[mi] = *(const bf16x8*)&Xs[m * 64 + (((kc * 4 + g) ^ (m & 7)) << 3)];
      }
      #pragma unroll
      for (int ni = 0; ni < NFRAG; ++ni) {
        int n = w * (16 * NFRAG) + ni * 16 + c;
        wf[ni] = *(const bf16x8*)&Ws[n * 64 + (((kc * 4 + g) ^ (n & 7)) << 3)];
      }
      #pragma unroll
      for (int mi = 0; mi < 7; ++mi)
        #pragma unroll
        for (int ni = 0; ni < NFRAG; ++ni)
          acc[mi][ni] = (ORIENT == 0)
            ? __builtin_amdgcn_mfma_f32_16x16x32_bf16(wf[ni], xf[mi], acc[mi][ni], 0, 0, 0)
            : __builtin_amdgcn_mfma_f32_16x16x32_bf16(xf[mi], wf[ni], acc[mi][ni], 0, 0, 0);
    }
    __syncthreads();
  }

  if (ORIENT == 0) {
    ushort* Ob = (ushort*)OutV;
    const int nbq = n0 + w * (16 * NFRAG);
    float bi[NFRAG][4];
    #pragma unroll
    for (int ni = 0; ni < NFRAG; ++ni)
      #pragma unroll
      for (int j = 0; j < 4; ++j) {
        int n = nbq + ni * 16 + g * 4 + j;
        bi[ni][j] = (n < Nreal) ? bias[n] : 0.f;
      }
    #pragma unroll
    for (int mi = 0; mi < 7; ++mi) {
      int m = m0 + mi * 16 + c;
      #pragma unroll
      for (int ni = 0; ni < NFRAG; ++ni) {
        int nb = nbq + ni * 16 + g * 4;
        if (nb >= Nstore) continue;
        float v[4];
        #pragma unroll
        for (int j = 0; j < 4; ++j) v[j] = acc[mi][ni][j] + bi[ni][j];
        if (EPI == 1) {
          #pragma unroll
          for (int j = 0; j < 4; ++j) v[j] = fmaxf(v[j], 0.f);
        } else if (EPI == 2) {
          #pragma unroll
          for (int j = 0; j < 4; ++j)
            v[j] = 0.5f * v[j] * (1.f + erff(v[j] * 0.70710678118654752f));
        } else if (EPI == 3) {
          uint2 cm = *(const uint2*)&Ob[(size_t)m * Nstore + nb];
          float cf[4];
          unpack4bf(cm, cf);
          #pragma unroll
          for (int j = 0; j < 4; ++j)
            v[j] = (1.f / (1.f + __expf(-v[j]))) * cf[j];
        } else if (EPI == 5) {
          int e = nb / 704; e = (e > 2) ? 2 : e;
          float sc = scales[bb * 3 + e];
          #pragma unroll
          for (int j = 0; j < 4; ++j)
            v[j] = 0.5f * v[j] * (1.f + erff(v[j] * 0.70710678118654752f)) * sc;
        }
        uint2 o = {pack2bf(v[0], v[1]), pack2bf(v[2], v[3])};
        *(uint2*)&Ob[(size_t)m * Nstore + nb] = o;
      }
    }
  } else {
    const int prow = m0 - bb * NPIX;
    float* Ob = (float*)OutV + (size_t)bb * CDIM * NPIX;
    const float* Rb = resid + (size_t)bb * CDIM * NPIX;
    float sc = (EPI == 4 && scales) ? scales[bb * 3] : 1.f;
    #pragma unroll
    for (int ni = 0; ni < NFRAG; ++ni) {
      int n = n0 + w * (16 * NFRAG) + ni * 16 + c;
      float bv = (EPI == 5) ? bias[(size_t)bb * CDIM + n] : bias[n];
      float cs = 0.f;
      #pragma unroll
      for (int mi = 0; mi < 7; ++mi) {
        int p = prow + mi * 16 + g * 4;
        size_t off = (size_t)n * NPIX + p;
        float4 r = *(const float4*)&Rb[off];
        f32x4 a = acc[mi][ni];
        float4 o = {r.x + sc * (a[0] + bv), r.y + sc * (a[1] + bv),
                    r.z + sc * (a[2] + bv), r.w + sc * (a[3] + bv)};
        *(float4*)&Ob[off] = o;
        if (POOL) cs += o.x + o.y + o.z + o.w;
        if (DUALBF) {
          size_t mg = (size_t)(m0 + mi * 16 + g * 4);
          pm_out[mg * CDIM + n] = f2bf(o.x);
          pm_out[(mg + 1) * CDIM + n] = f2bf(o.y);
          pm_out[(mg + 2) * CDIM + n] = f2bf(o.z);
          pm_out[(mg + 3) * CDIM + n] = f2bf(o.w);
        }
      }
      if (POOL) {
        cs += __shfl_xor(cs, 16);
        cs += __shfl_xor(cs, 32);
        if (g == 0) atomicAdd(pool_out + (size_t)bb * CDIM + n, cs);
      }
    }
  }
}

// ---------------------------------------------------------------------------
// transpose V out of qkvbf:  [b][p][1024+c] bf16 -> vbf [b][c][784] bf16
__global__ __launch_bounds__(256) void vtr_k(const ushort* __restrict__ qkvbf,
                                             ushort* __restrict__ vbf) {
  const int p0 = blockIdx.x * 64, c0 = blockIdx.y * 64, b = blockIdx.z;
  __shared__ ushort T[64][72];
  for (int idx = threadIdx.x; idx < 512; idx += 256) {
    int pl = idx >> 3, cq = idx & 7;
    int p = p0 + pl;
    uint4 v = {0u, 0u, 0u, 0u};
    if (p < NPIX)
      v = *(const uint4*)(qkvbf + (size_t)(b * NPIX + p) * C3 + 1024 + c0 + cq * 8);
    *(uint4*)&T[pl][cq * 8] = v;
  }
  __syncthreads();
  for (int idx = threadIdx.x; idx < 512; idx += 256) {
    int cl = idx >> 3, pq = idx & 7;
    if (p0 + pq * 8 < NPIX) {
      ushort tmp[8];
      #pragma unroll
      for (int i = 0; i < 8; ++i) tmp[i] = T[pq * 8 + i][cl];
      *(uint4*)(vbf + ((size_t)(b * CDIM + c0 + cl)) * NPIX + p0 + pq * 8) =
          *(const uint4*)&tmp[0];
    }
  }
}

// ---------------------------------------------------------------------------
// MFMA flash attention: 32 q rows / wave (2 chunks, shared K/V frags),
// register software-pipeline, exp2 softmax, defer-max, setprio.
// Grid 896: b = (bid&7) + 8*(i/56).
struct KFr { bf16x8 a0, a1, b0, b1; };
struct VFr { bf16x8 v0, v1, v2, v3; };
struct BFr { uint2 sl, fl, sh, fh; };

__global__ __launch_bounds__(256) void attn_mfma_k(const ushort* __restrict__ qkvbf,
                                                   const ushort* __restrict__ vbf,
                                                   const ushort* __restrict__ sprpb,
                                                   const ushort* __restrict__ fpb,
                                                   ushort* __restrict__ obf) {
  const int bid = blockIdx.x;
  const int xcd = bid & 7;
  const int i = bid >> 3;
  const int b = xcd + 8 * (i / 56);
  const int r = i % 56;
  const int h = r & 7;
  const int qt = r >> 3;
  const int w = threadIdx.x >> 6, lane = threadIdx.x & 63;
  const int g = lane >> 4, c = lane & 15;
  const int q0 = qt * 128 + w * 32;
  if (q0 >= NPIX) return;
  const bool hasB = (q0 + 16) < NPIX;
  const int qA = q0 + c;
  const int qB = q0 + 16 + c;

  __shared__ uint BL[4][2][384];
  uint* bwA = BL[w][0];
  uint* bwB = BL[w][1];

  const ushort* qpA = qkvbf + (size_t)(b * NPIX + qA) * C3 + h * 64 + g * 8;
  const bf16x8 qfA0 = *(const bf16x8*)qpA;
  const bf16x8 qfA1 = *(const bf16x8*)(qpA + 32);
  bf16x8 qfB0 = qfA0, qfB1 = qfA1;
  if (hasB) {
    const ushort* qpB = qkvbf + (size_t)(b * NPIX + qB) * C3 + h * 64 + g * 8;
    qfB0 = *(const bf16x8*)qpB;
    qfB1 = *(const bf16x8*)(qpB + 32);
  }

  const ushort* kbase = qkvbf + (size_t)b * NPIX * C3 + 512 + h * 64 + g * 8;
  const ushort* vbase = vbf + ((size_t)b * CDIM + h * 64) * NPIX;
  const ushort* sprA = sprpb + ((size_t)h * NPIX + qA) * NPIX;
  const ushort* sprB = sprpb + ((size_t)h * NPIX + (hasB ? qB : qA)) * NPIX;
  const ushort* fpA = fpb + ((size_t)b * NPIX + qA) * NPIX;
  const ushort* fpB = fpb + ((size_t)b * NPIX + (hasB ? qB : qA)) * NPIX;

  auto load_k = [&](int m0, bool tfull) -> KFr {
    KFr k;
    const ushort* kp = kbase + (size_t)(m0 + c) * C3;
    k.a0 = *(const bf16x8*)kp;
    k.a1 = *(const bf16x8*)(kp + 32);
    const ushort* kp1 = kp + (tfull ? (size_t)16 * C3 : 0);
    k.b0 = *(const bf16x8*)kp1;
    k.b1 = *(const bf16x8*)(kp1 + 32);
    return k;
  };
  auto load_v = [&](int m0) -> VFr {
    VFr v;
    const ushort* vp = vbase + (size_t)c * NPIX + m0 + g * 8;
    v.v0 = *(const bf16x8*)(vp);
    v.v1 = *(const bf16x8*)(vp + (size_t)16 * NPIX);
    v.v2 = *(const bf16x8*)(vp + (size_t)32 * NPIX);
    v.v3 = *(const bf16x8*)(vp + (size_t)48 * NPIX);
    return v;
  };
  auto load_b = [&](const ushort* spr, const ushort* fp, int m0) -> BFr {
    BFr x;
    x.sl = *(const uint2*)(spr + m0 + g * 4);
    x.fl = *(const uint2*)(fp + m0 + g * 4);
    x.sh = *(const uint2*)(spr + m0 + 16 + g * 4);
    x.fh = *(const uint2*)(fp + m0 + 16 + g * 4);
    return x;
  };

  f32x4 oA0 = {0.f, 0.f, 0.f, 0.f}, oA1 = oA0, oA2 = oA0, oA3 = oA0;
  f32x4 oB0 = oA0, oB1 = oA0, oB2 = oA0, oB3 = oA0;
  float MA = -1e30f, LA = 0.f, MB = -1e30f, LB = 0.f;

  KFr kc = load_k(0, true);
  VFr vc = load_v(0);
  BFr bcA = load_b(sprA, fpA, 0);
  BFr bcB = bcA;
  if (hasB) bcB = load_b(sprB, fpB, 0);

  for (int ms = 0; ms < 25; ++ms) {
    const int m0 = ms * 32;
    const bool full = (ms < 24);

    KFr kn; VFr vn; BFr bnA, bnB;
    if (full) {
      const int nm0 = m0 + 32;
      kn = load_k(nm0, ms + 1 < 24);
      vn = load_v(nm0);
      bnA = load_b(sprA, fpA, nm0);
      if (hasB) bnB = load_b(sprB, fpB, nm0);
    }

    // ---- chunk A ----
    f32x4 sA0 = {0.f, 0.f, 0.f, 0.f}, sA1 = sA0;
    __builtin_amdgcn_s_setprio(1);
    sA0 = __builtin_amdgcn_mfma_f32_16x16x32_bf16(kc.a0, qfA0, sA0, 0, 0, 0);
    sA0 = __builtin_amdgcn_mfma_f32_16x16x32_bf16(kc.a1, qfA1, sA0, 0, 0, 0);
    if (full) {
      sA1 = __builtin_amdgcn_mfma_f32_16x16x32_bf16(kc.b0, qfA0, sA1, 0, 0, 0);
      sA1 = __builtin_amdgcn_mfma_f32_16x16x32_bf16(kc.b1, qfA1, sA1, 0, 0, 0);
    }
    __builtin_amdgcn_s_setprio(0);
    {
      float vA0[4], vA1[4];
      float spv[4], fpv[4];
      unpack4bf(bcA.sl, spv);
      unpack4bf(bcA.fl, fpv);
      #pragma unroll
      for (int j = 0; j < 4; ++j) vA0[j] = fmaf(sA0[j], KSCL, spv[j]) * fpv[j];
      if (full) {
        unpack4bf(bcA.sh, spv);
        unpack4bf(bcA.fh, fpv);
        #pragma unroll
        for (int j = 0; j < 4; ++j) vA1[j] = fmaf(sA1[j], KSCL, spv[j]) * fpv[j];
      }
      float tm = fmaxf(fmaxf(vA0[0], vA0[1]), fmaxf(vA0[2], vA0[3]));
      if (full) tm = fmaxf(tm, fmaxf(fmaxf(vA1[0], vA1[1]), fmaxf(vA1[2], vA1[3])));
      tm = fmaxf(tm, __shfl_xor(tm, 16));
      tm = fmaxf(tm, __shfl_xor(tm, 32));
      if (__any(tm > MA)) {
        const float nM = fmaxf(MA, tm);
        const float fac = __builtin_amdgcn_exp2f(MA - nM);
        LA *= fac;
        #pragma unroll
        for (int j = 0; j < 4; ++j) { oA0[j] *= fac; oA1[j] *= fac; oA2[j] *= fac; oA3[j] *= fac; }
        MA = nM;
      }
      float p0v[4], p1v[4];
      float ps = 0.f;
      #pragma unroll
      for (int j = 0; j < 4; ++j) { p0v[j] = __builtin_amdgcn_exp2f(vA0[j] - MA); ps += p0v[j]; }
      if (full) {
        #pragma unroll
        for (int j = 0; j < 4; ++j) { p1v[j] = __builtin_amdgcn_exp2f(vA1[j] - MA); ps += p1v[j]; }
      }
      ps += __shfl_xor(ps, 16);
      ps += __shfl_xor(ps, 32);
      LA += ps;
      uint2 wlo, whi;
      wlo.x = pack2bf(p0v[0], p0v[1]);
      wlo.y = pack2bf(p0v[2], p0v[3]);
      whi.x = full ? pack2bf(p1v[0], p1v[1]) : 0u;
      whi.y = full ? pack2bf(p1v[2], p1v[3]) : 0u;
      *(uint2*)&bwA[lane * 6] = wlo;
      *(uint2*)&bwA[lane * 6 + 2] = whi;
    }

    // ---- chunk B ----
    if (hasB) {
      f32x4 sB0 = {0.f, 0.f, 0.f, 0.f}, sB1 = sB0;
      __builtin_amdgcn_s_setprio(1);
      sB0 = __builtin_amdgcn_mfma_f32_16x16x32_bf16(kc.a0, qfB0, sB0, 0, 0, 0);
      sB0 = __builtin_amdgcn_mfma_f32_16x16x32_bf16(kc.a1, qfB1, sB0, 0, 0, 0);
      if (full) {
        sB1 = __builtin_amdgcn_mfma_f32_16x16x32_bf16(kc.b0, qfB0, sB1, 0, 0, 0);
        sB1 = __builtin_amdgcn_mfma_f32_16x16x32_bf16(kc.b1, qfB1, sB1, 0, 0, 0);
      }
      __builtin_amdgcn_s_setprio(0);
      float vB0[4], vB1[4];
      float spv[4], fpv[4];
      unpack4bf(bcB.sl, spv);
      unpack4bf(bcB.fl, fpv);
      #pragma unroll
      for (int j = 0; j < 4; ++j) vB0[j] = fmaf(sB0[j], KSCL, spv[j]) * fpv[j];
      if (full) {
        unpack4bf(bcB.sh, spv);
        unpack4bf(bcB.fh, fpv);
        #pragma unroll
        for (int j = 0; j < 4; ++j) vB1[j] = fmaf(sB1[j], KSCL, spv[j]) * fpv[j];
      }
      float tm = fmaxf(fmaxf(vB0[0], vB0[1]), fmaxf(vB0[2], vB0[3]));
      if (full) tm = fmaxf(tm, fmaxf(fmaxf(vB1[0], vB1[1]), fmaxf(vB1[2], vB1[3])));
      tm = fmaxf(tm, __shfl_xor(tm, 16));
      tm = fmaxf(tm, __shfl_xor(tm, 32));
      if (__any(tm > MB)) {
        const float nM = fmaxf(MB, tm);
        const float fac = __builtin_amdgcn_exp2f(MB - nM);
        LB *= fac;
        #pragma unroll
        for (int j = 0; j < 4; ++j) { oB0[j] *= fac; oB1[j] *= fac; oB2[j] *= fac; oB3[j] *= fac; }
        MB = nM;
      }
      float p0v[4], p1v[4];
      float ps = 0.f;
      #pragma unroll
      for (int j = 0; j < 4; ++j) { p0v[j] = __builtin_amdgcn_exp2f(vB0[j] - MB); ps += p0v[j]; }
      if (full) {
        #pragma unroll
        for (int j = 0; j < 4; ++j) { p1v[j] = __builtin_amdgcn_exp2f(vB1[j] - MB); ps += p1v[j]; }
      }
      ps += __shfl_xor(ps, 16);
      ps += __shfl_xor(ps, 32);
      LB += ps;
      uint2 wlo, whi;
      wlo.x = pack2bf(p0v[0], p0v[1]);
      wlo.y = pack2bf(p0v[2], p0v[3]);
      whi.x = full ? pack2bf(p1v[0], p1v[1]) : 0u;
      whi.y = full ? pack2bf(p1v[2], p1v[3]) : 0u;
      *(uint2*)&bwB[lane * 6] = wlo;
      *(uint2*)&bwB[lane * 6 + 2] = whi;
    }

    // ---- PV for both chunks (shared V) ----
    const int f = g >> 1;
    const int slo = 32 * (g & 1) + c;
    uint2 blo = *(const uint2*)&bwA[slo * 6 + f * 2];
    uint2 bhi = *(const uint2*)&bwA[(slo + 16) * 6 + f * 2];
    uint4 bba = {blo.x, blo.y, bhi.x, bhi.y};
    const bf16x8 pfA = __builtin_bit_cast(bf16x8, bba);
    __builtin_amdgcn_s_setprio(1);
    oA0 = __builtin_amdgcn_mfma_f32_16x16x32_bf16(vc.v0, pfA, oA0, 0, 0, 0);
    oA1 = __builtin_amdgcn_mfma_f32_16x16x32_bf16(vc.v1, pfA, oA1, 0, 0, 0);
    oA2 = __builtin_amdgcn_mfma_f32_16x16x32_bf16(vc.v2, pfA, oA2, 0, 0, 0);
    oA3 = __builtin_amdgcn_mfma_f32_16x16x32_bf16(vc.v3, pfA, oA3, 0, 0, 0);
    __builtin_amdgcn_s_setprio(0);
    if (hasB) {
      uint2 clo = *(const uint2*)&bwB[slo * 6 + f * 2];
      uint2 chi = *(const uint2*)&bwB[(slo + 16) * 6 + f * 2];
      uint4 bbb = {clo.x, clo.y, chi.x, chi.y};
      const bf16x8 pfB = __builtin_bit_cast(bf16x8, bbb);
      __builtin_amdgcn_s_setprio(1);
      oB0 = __builtin_amdgcn_mfma_f32_16x16x32_bf16(vc.v0, pfB, oB0, 0, 0, 0);
      oB1 = __builtin_amdgcn_mfma_f32_16x16x32_bf16(vc.v1, pfB, oB1, 0, 0, 0);
      oB2 = __builtin_amdgcn_mfma_f32_16x16x32_bf16(vc.v2, pfB, oB2, 0, 0, 0);
      oB3 = __builtin_amdgcn_mfma_f32_16x16x32_bf16(vc.v3, pfB, oB3, 0, 0, 0);
      __builtin_amdgcn_s_setprio(0);
    }

    if (full) { kc = kn; vc = vn; bcA = bnA; if (hasB) bcB = bnB; }
  }

  {
    const float invL = 1.f / LA;
    ushort* dst = obf + (size_t)(b * NPIX + qA) * CDIM + h * 64 + g * 4;
    f32x4 ot[4] = {oA0, oA1, oA2, oA3};
    #pragma unroll
    for (int t2 = 0; t2 < 4; ++t2) {
      uint2 o = {pack2bf(ot[t2][0] * invL, ot[t2][1] * invL),
                 pack2bf(ot[t2][2] * invL, ot[t2][3] * invL)};
      *(uint2*)(dst + t2 * 16) = o;
    }
  }
  if (hasB) {
    const float invL = 1.f / LB;
    ushort* dst = obf + (size_t)(b * NPIX + qB) * CDIM + h * 64 + g * 4;
    f32x4 ot[4] = {oB0, oB1, oB2, oB3};
    #pragma unroll
    for (int t2 = 0; t2 < 4; ++t2) {
      uint2 o = {pack2bf(ot[t2][0] * invL, ot[t2][1] * invL),
                 pack2bf(ot[t2][2] * invL, ot[t2][3] * invL)};
      *(uint2*)(dst + t2 * 16) = o;
    }
  }
}

// ---------------------------------------------------------------------------
// Sliding-window fused LN2 + depthwise conv (3x3/5x5/7x7) -> cat pm bf16.
__device__ __forceinline__ float bf2f_s(ushort u) { return bf2f(u); }

template <int R>
__device__ __forceinline__ void conv_pass(const ushort* __restrict__ plane_ci,
                                          const float* __restrict__ wl_ci,
                                          float bv, int slot,
                                          ushort (*__restrict__ outb)[16], int ci) {
  constexpr int K = 2 * R + 1;
  float wreg[K * K];
  #pragma unroll
  for (int i = 0; i < K * K; ++i) wreg[i] = wl_ci[i];
  #pragma unroll
  for (int r7 = 0; r7 < 7; ++r7) {
    const int run = slot + r7 * 16;
    const int y = run >> 2, x0 = (run & 3) * 7;
    float acc[7];
    #pragma unroll
    for (int i = 0; i < 7; ++i) acc[i] = bv;
    #pragma unroll
    for (int dy = 0; dy < K; ++dy) {
      const ushort* rp = plane_ci + (y + 3 - R + dy) * 34 + (x0 + 3 - R);
      float win[7 + 2 * R];
      #pragma unroll
      for (int k = 0; k < 7 + 2 * R; ++k) win[k] = bf2f_s(rp[k]);
      #pragma unroll
      for (int i = 0; i < 7; ++i)
        #pragma unroll
        for (int k = 0; k < K; ++k)
          acc[i] = fmaf(win[i + k], wreg[dy * K + k], acc[i]);
    }
    #pragma unroll
    for (int i = 0; i < 7; ++i) outb[y * 28 + x0 + i][ci] = f2bf(acc[i]);
  }
}

__global__ __launch_bounds__(256) void dwln_k(const float* __restrict__ x2,
    const float* __restrict__ ust, const float* __restrict__ rst,
    const float* __restrict__ ad, const float* __restrict__ n2w,
    const float* __restrict__ n2b,
    const float* __restrict__ ew, const float* __restrict__ eb,
    const float* __restrict__ nw, const float* __restrict__ nb,
    const float* __restrict__ mw, const float* __restrict__ mb,
    ushort* __restrict__ cat) {
  const int cg = blockIdx.x, b = blockIdx.y;
  const int c0 = cg * 16;
  const int t = threadIdx.x;
  const int ci = t & 15, slot = t >> 4;

  __shared__ ushort plane[16][1156];
  __shared__ ushort outb[784][16];
  __shared__ float Wl[16 * 49];
  __shared__ float LWs[16], LBs[16];

  {
    uint* pz = (uint*)&plane[0][0];
    for (int i = t; i < 16 * 1156 / 2; i += 256) pz[i] = 0u;
  }
  if (t < 16) {
    int cc = c0 + t;
    float aw = ad[b * 1024 + cc], ab = ad[b * 1024 + 512 + cc];
    LWs[t] = n2w[cc] * (1.f + aw);
    LBs[t] = n2b[cc] + ab;
  }
  __syncthreads();

  {
    float uu[4], rr[4];
    #pragma unroll
    for (int j = 0; j < 4; ++j) {
      int p = t + j * 256;
      if (p < NPIX) {
        uu[j] = ust[(size_t)b * NPIX + p];
        rr[j] = rst[(size_t)b * NPIX + p];
      }
    }
    for (int cc = 0; cc < 16; ++cc) {
      const float* xp = x2 + ((size_t)(b * CDIM + c0 + cc)) * NPIX;
      float lw = LWs[cc], lb = LBs[cc];
      #pragma unroll
      for (int j = 0; j < 4; ++j) {
        int p = t + j * 256;
        if (p < NPIX) {
          int y = p / 28, xx2 = p - y * 28;
          plane[cc][(y + 3) * 34 + xx2 + 3] = f2bf(lw * (xp[p] - uu[j]) * rr[j] + lb);
        }
      }
    }
  }
  __syncthreads();

  #pragma unroll 1
  for (int cv = 0; cv < 3; ++cv) {
    const float* gw = (cv == 0) ? ew : (cv == 1) ? nw : mw;
    const float* gb = (cv == 0) ? eb : (cv == 1) ? nb : mb;
    const int K2 = (cv == 0) ? 9 : (cv == 1) ? 25 : 49;
    for (int i = t; i < 16 * K2; i += 256) {
      int cc = i / K2, k = i - cc * K2;
      Wl[cc * K2 + k] = gw[(size_t)(c0 + cc) * K2 + k];
    }
    __syncthreads();
    float bv = gb[c0 + ci];
    if (cv == 0)      conv_pass<1>(&plane[ci][0], &Wl[ci * 9],  bv, slot, outb, ci);
    else if (cv == 1) conv_pass<2>(&plane[ci][0], &Wl[ci * 25], bv, slot, outb, ci);
    else              conv_pass<3>(&plane[ci][0], &Wl[ci * 49], bv, slot, outb, ci);
    __syncthreads();
    for (int idx = t; idx < NPIX * 2; idx += 256) {
      int p = idx >> 1, half = idx & 1;
      uint4 v = *(const uint4*)&outb[p][half * 8];
      *(uint4*)(cat + ((size_t)(b * NPIX + p)) * C3 + cv * 512 + c0 + half * 8) = v;
    }
    __syncthreads();
  }
}

// ---------------------------------------------------------------------------
__global__ __launch_bounds__(64) void router_k(const float* __restrict__ pooled,
                                               const float* __restrict__ rw,
                                               const float* __restrict__ rb,
                                               float* __restrict__ r) {
  int b = blockIdx.x, lane = threadIdx.x;
  float a0 = 0.f, a1 = 0.f, a2 = 0.f;
  for (int k = lane; k < CDIM; k += 64) {
    float p = pooled[b * CDIM + k] * (1.f / NPIX);
    a0 += rw[k] * p;
    a1 += rw[CDIM + k] * p;
    a2 += rw[2 * CDIM + k] * p;
  }
  #pragma unroll
  for (int off = 32; off; off >>= 1) {
    a0 += __shfl_down(a0, off);
    a1 += __shfl_down(a1, off);
    a2 += __shfl_down(a2, off);
  }
  if (lane == 0) {
    float l0 = a0 + rb[0], l1 = a1 + rb[1], l2 = a2 + rb[2];
    float mx = fmaxf(l0, fmaxf(l1, l2));
    float e0 = __expf(l0 - mx), e1 = __expf(l1 - mx), e2 = __expf(l2 - mx);
    float inv = 1.f / (e0 + e1 + e2);
    r[b * 3 + 0] = e0 * inv;
    r[b * 3 + 1] = e1 * inv;
    r[b * 3 + 2] = e2 * inv;
  }
}

// ---------------------------------------------------------------------------
extern "C" void kernel_launch(void* const* d_in, const int* in_sizes, int n_in,
                              void* d_out, int out_size, void* d_ws, size_t ws_size,
                              hipStream_t stream) {
  (void)in_sizes; (void)n_in; (void)out_size; (void)ws_size;
  const float* x         = (const float*)d_in[0];
  const float* fpri      = (const float*)d_in[1];
  const float* n1_w      = (const float*)d_in[2];
  const float* n1_b      = (const float*)d_in[3];
  const float* n1_a1w    = (const float*)d_in[4];
  const float* n1_a1b    = (const float*)d_in[5];
  const float* n1_a2w    = (const float*)d_in[6];
  const float* n1_a2b    = (const float*)d_in[7];
  const float* n2_w      = (const float*)d_in[8];
  const float* n2_b      = (const float*)d_in[9];
  const float* n2_a1w    = (const float*)d_in[10];
  const float* n2_a1b    = (const float*)d_in[11];
  const float* n2_a2w    = (const float*)d_in[12];
  const float* n2_a2b    = (const float*)d_in[13];
  const float* qkv_w     = (const float*)d_in[14];
  const float* qkv_b     = (const float*)d_in[15];
  const float* rpb_table = (const float*)d_in[16];
  const float* sprior    = (const float*)d_in[17];
  const float* proj_w    = (const float*)d_in[18];
  const float* proj_b    = (const float*)d_in[19];
  const float* eye_w     = (const float*)d_in[20];
  const float* eye_b     = (const float*)d_in[21];
  const float* nose_w    = (const float*)d_in[22];
  const float* nose_b    = (const float*)d_in[23];
  const float* mouth_w   = (const float*)d_in[24];
  const float* mouth_b   = (const float*)d_in[25];
  const float* fusion_w  = (const float*)d_in[26];
  const float* fusion_b  = (const float*)d_in[27];
  const float* gate1_w   = (const float*)d_in[28];
  const float* gate1_b   = (const float*)d_in[29];
  const float* gate2_w   = (const float*)d_in[30];
  const float* gate2_b   = (const float*)d_in[31];
  const float* e1w[3] = {(const float*)d_in[32], (const float*)d_in[36], (const float*)d_in[40]};
  const float* e1b[3] = {(const float*)d_in[33], (const float*)d_in[37], (const float*)d_in[41]};
  const float* e2w[3] = {(const float*)d_in[34], (const float*)d_in[38], (const float*)d_in[42]};
  const float* e2b[3] = {(const float*)d_in[35], (const float*)d_in[39], (const float*)d_in[43]};
  const float* router_w  = (const float*)d_in[44];
  const float* router_b  = (const float*)d_in[45];

  float* ws    = (float*)d_ws;
  ushort* xpm  = (ushort*)(ws + OFF_XPM);
  ushort* wb   = (ushort*)(ws + OFF_W);
  ushort* r2u  = (ushort*)(ws + OFF_R2);
  ushort* vbf  = (ushort*)(ws + OFF_VBF);
  ushort* obf  = (ushort*)(ws + OFF_OBF);
  float* x2    = ws + OFF_X2;
  float* x3    = ws + OFF_X3;
  float* pld   = ws + OFF_PL;
  float* adb   = ws + OFF_AD;
  float* rbuf  = ws + OFF_RB;
  float* ust   = ws + OFF_US;
  float* rst   = ws + OFF_RS;
  float* outp  = (float*)d_out;

  ushort* qkvw  = wb + WOFF_QKV;
  ushort* projw = wb + WOFF_PROJ;
  ushort* g1w   = wb + WOFF_G1;
  ushort* g2w   = wb + WOFF_G2;
  ushort* fusw  = wb + WOFF_FUS;
  ushort* e1cat = wb + WOFF_E1;
  ushort* e2cat = (ushort*)(ws + OFF_E2C);
  float* be     = adb;
  float* e1bcat = adb + 8192;

  ushort* fpbf   = (ushort*)x2;
  ushort* sprpbf = (ushort*)x3;

  // --- weight conversion + expert stacking (704-aligned) ---
  CvtDesc D;
  auto seg = [&](int s2, const float* src, ushort* dst, int rows, int sk, int dk,
                 int ds, int rr) {
    D.s[s2] = src; D.d[s2] = dst; D.rows[s2] = rows; D.sk[s2] = sk;
    D.dk[s2] = dk; D.ds[s2] = ds; D.rr[s2] = rr;
  };
  seg(0, qkv_w,    qkvw,  1536, 512,  512,  512,  1536);
  seg(1, proj_w,   projw, 512,  512,  512,  512,  512);
  seg(2, gate1_w,  g1w,   128,  512,  512,  512,  128);
  seg(3, gate2_w,  g2w,   1536, 128,  128,  128,  1536);
  seg(4, fusion_w, fusw,  512,  1536, 1536, 1536, 512);
  for (int e = 0; e < 3; ++e) {
    seg(5 + e, e1w[e], e1cat + (size_t)e * 704 * 512, 704, 512, 512, 512, 682);
    seg(8 + e, e2w[e], e2cat + (size_t)e * 704,       512, 682, 704, 2112, 512);
  }
  cvt_w_k<<<dim3(512, 11), 256, 0, stream>>>(D);

  // --- attention bias prep ---
  sprpb_k<<<dim3(NPIX, NHEAD), 256, 0, stream>>>(sprior, rpb_table, sprpbf);
  fpcvt_k<<<9604, 256, 0, stream>>>(fpri, fpbf);

  // --- LN1 ---
  pool_mean_k<<<dim3(CDIM, 16), 64, 0, stream>>>(x, pld);
  adapt_mlp_k<<<16, 256, 0, stream>>>(pld, n1_a1w, n1_a1b, n1_a2w, n1_a2b, adb);
  ln_pm_k<0><<<dim3(25, 16), 256, 0, stream>>>(x, n1_w, n1_b, adb, xpm, nullptr, nullptr);

  // --- attention ---
  mgemm_k<0, 0, 0, 0, 128><<<1344, 256, 0, stream>>>(xpm, qkvw, qkv_b, nullptr, nullptr,
                                                     r2u, nullptr, nullptr, 512, 1536, 1536);
  vtr_k<<<dim3(13, 8, 16), 256, 0, stream>>>(r2u, vbf);
  attn_mfma_k<<<896, 256, 0, stream>>>(r2u, vbf, sprpbf, fpbf, obf);
  hipMemsetAsync(pld, 0, 16 * CDIM * sizeof(float), stream);
  mgemm_k<1, 4, 1, 0, 64><<<896, 256, 0, stream>>>(obf, projw, proj_b, x, nullptr,
                                                   x2, pld, nullptr, 512, 512, 512);

  // --- LN2 + token mixer ---
  adapt_mlp_k<<<16, 256, 0, stream>>>(pld, n2_a1w, n2_a1b, n2_a2w, n2_a2b, adb);
  ln_pm_k<1><<<dim3(25, 16), 256, 0, stream>>>(x2, n2_w, n2_b, adb, xpm, ust, rst);
  dwln_k<<<dim3(32, 16), 256, 0, stream>>>(x2, ust, rst, adb, n2_w, n2_b,
                                           eye_w, eye_b, nose_w, nose_b, mouth_w, mouth_b,
                                           r2u);
  mgemm_k<0, 1, 0, 0, 64><<<224, 256, 0, stream>>>(xpm, g1w, gate1_b, nullptr, nullptr,
                                                   obf, nullptr, nullptr, 512, 128, 128);
  mgemm_k<0, 3, 0, 0, 128><<<1344, 256, 0, stream>>>(obf, g2w, gate2_b, nullptr, nullptr,
                                                     r2u, nullptr, nullptr, 128, 1536, 1536);
  hipMemsetAsync(pld, 0, 16 * CDIM * sizeof(float), stream);
  mgemm_k<1, 4, 1, 1, 64><<<896, 256, 0, stream>>>(r2u, fusw, fusion_b, x2, nullptr,
                                                   x3, pld, xpm, 1536, 512, 512);

  // --- MoE (fused: 2 stacked GEMMs; x3bf already in xpm via DUALBF) ---
  router_k<<<16, 64, 0, stream>>>(pld, router_w, router_b, rbuf);
  biaseff_k<<<17, 512, 0, stream>>>(rbuf, e2b[0], e2b[1], e2b[2],
                                    e1b[0], e1b[1], e1b[2], be, e1bcat);
  mgemm_k<0, 5, 0, 0, 128><<<1904, 256, 0, stream>>>(xpm, e1cat, e1bcat, nullptr, rbuf,
                                                     r2u, nullptr, nullptr, 512, 2112, 2112);
  mgemm_k<1, 5, 0, 0, 64><<<896, 256, 0, stream>>>(r2u, e2cat, be, x3, nullptr,
                                                   outp, nullptr, nullptr, 2112, 512, 512);
}